// Round 3
// baseline (104.768 us; speedup 1.0000x reference)
//
#include <hip/hip_runtime.h>
#include <math.h>

#define NF 256      // in_features
#define NT 256      // num_trees
#define ND 6        // depth
#define NB 2048     // batch
#define NCOL (NT * ND)   // 1536
#define NLEAF 64         // 2^depth

typedef __attribute__((ext_vector_type(8))) short bf16x8;         // MFMA A/B frag
typedef __attribute__((ext_vector_type(4))) float f32x4;          // MFMA C/D frag
typedef __attribute__((ext_vector_type(8))) unsigned short u16x8; // 16B chunk

__device__ inline unsigned short f2bf(float f) {   // round-to-nearest-even bf16
    unsigned u = __float_as_uint(f);
    u += 0x7fffu + ((u >> 16) & 1u);
    return (unsigned short)(u >> 16);
}
__device__ inline float bf2f(unsigned short h) {
    return __uint_as_float(((unsigned)h) << 16);
}

// ---------------------------------------------------------------------------
// Kernel 1: sparsemax per (tree,depth) column via Michelot fixed-point.
// One wave per column, 4 elements/lane, shuffle reductions only (no LDS).
// Output TRANSPOSED [col][feature] bf16 hi/lo.   (EXACT round-0 version)
// ---------------------------------------------------------------------------
__global__ __launch_bounds__(256) void sparsemax_michelot(
    const float* __restrict__ fsl,       // [NF, NCOL]
    unsigned short* __restrict__ fs_hi,  // [NCOL, NF]
    unsigned short* __restrict__ fs_lo)  // [NCOL, NF]
{
    const int lane = threadIdx.x & 63;
    const int col  = blockIdx.x * 4 + (threadIdx.x >> 6);

    float x[4];
    #pragma unroll
    for (int j = 0; j < 4; j++)
        x[j] = fsl[(lane + 64 * j) * NCOL + col];

    // max over 256
    float mx = fmaxf(fmaxf(x[0], x[1]), fmaxf(x[2], x[3]));
    #pragma unroll
    for (int off = 32; off > 0; off >>= 1)
        mx = fmaxf(mx, __shfl_xor(mx, off));
    #pragma unroll
    for (int j = 0; j < 4; j++) x[j] -= mx;

    // tau_0 = (sum - 1)/256
    float s = (x[0] + x[1]) + (x[2] + x[3]);
    #pragma unroll
    for (int off = 32; off > 0; off >>= 1)
        s += __shfl_xor(s, off);
    float tau = (s - 1.0f) / 256.0f;

    // Michelot: S <- {x > tau}; tau <- (sum_S - 1)/|S|; stop when |S| stable.
    int prev = 256;
    for (int it = 0; it < 64; it++) {
        float ss = 0.0f, cc = 0.0f;
        #pragma unroll
        for (int j = 0; j < 4; j++)
            if (x[j] > tau) { ss += x[j]; cc += 1.0f; }
        #pragma unroll
        for (int off = 32; off > 0; off >>= 1) {
            ss += __shfl_xor(ss, off);
            cc += __shfl_xor(cc, off);
        }
        const int c = (int)cc;
        if (c == prev) break;
        prev = c;
        tau = (ss - 1.0f) / cc;
    }

    #pragma unroll
    for (int j = 0; j < 4; j++) {
        const float v = fmaxf(x[j] - tau, 0.0f);
        const unsigned short h = f2bf(v);
        fs_hi[col * NF + lane + 64 * j] = h;
        fs_lo[col * NF + lane + 64 * j] = f2bf(v - bf2f(h));
    }
}

// ---------------------------------------------------------------------------
// Kernel 2: fused split-bf16 MFMA GEMM + tree evaluation.
// K-loop/staging: EXACT round-0 structure (in-register fp32 split, padded
// single LDS buffer). Epilogue: fold-down contraction + coalesced stores.
// ---------------------------------------------------------------------------
#define TM 64
#define TN 96
#define TK 32
#define PK (TK + 8)   // padded LDS pitch (u16) to break bank conflicts

union SMem {
    struct {
        unsigned short Ah[TM][PK], Al[TM][PK];
        unsigned short Bh[TN][PK], Bl[TN][PK];
    } st;                                   // 25.0 KB (K-loop)
    struct {
        float fv[TM][TN + 1];               // 64 x 97
        float resp[16][NLEAF + 4];          // padded rows (272 B, 16B-aligned)
        float th[16 * ND];
        float sc[16 * ND];
    } ep;                                   // ~29.3 KB (epilogue)
};

__global__ __launch_bounds__(256) void gemm_tree_kernel(
    const float* __restrict__ x,             // [NB, NF] fp32
    const unsigned short* __restrict__ Bh,   // fs hi [NCOL, NF]
    const unsigned short* __restrict__ Bl,   // fs lo [NCOL, NF]
    const float* __restrict__ thr,           // [NT, ND]
    const float* __restrict__ ltemp,         // [NT, ND]
    const float* __restrict__ resp_g,        // [NT, 1, NLEAF]
    float* __restrict__ out)                 // [NB, NT]
{
    __shared__ SMem sm;

    const int tid  = threadIdx.x;
    const int lane = tid & 63;
    const int w    = tid >> 6;
    const int wm   = w & 1;          // wave M pos (0..1) -> 32 rows
    const int wn   = w >> 1;         // wave N pos (0..1) -> 48 cols
    const int bm0  = blockIdx.y * TM;
    const int bn0  = blockIdx.x * TN;
    const int t0   = blockIdx.x * 16;    // first tree of this block

    const int l15  = lane & 15;
    const int quad = lane >> 4;

    // A staging coords: thread -> (row 0..63, kseg 0/8/16/24)
    const int arow  = tid >> 2;
    const int akseg = (tid & 3) * 8;
    // B staging coords: 128 threads hi, 128 threads lo; 32 rows x 32 k per pass
    const int bhalf = tid >> 7;
    const int brow  = (tid & 127) >> 2;
    const int bkseg = (tid & 3) * 8;

    f32x4 acc[2][3] = {};

    for (int k0 = 0; k0 < NF; k0 += TK) {
        // ---- A: load fp32, split to bf16 hi/lo in-register ----
        {
            const float4 v0 = *(const float4*)&x[(bm0 + arow) * NF + k0 + akseg];
            const float4 v1 = *(const float4*)&x[(bm0 + arow) * NF + k0 + akseg + 4];
            const float vv[8] = {v0.x, v0.y, v0.z, v0.w, v1.x, v1.y, v1.z, v1.w};
            u16x8 hi, lo;
            #pragma unroll
            for (int j = 0; j < 8; j++) {
                const unsigned short h = f2bf(vv[j]);
                hi[j] = h;
                lo[j] = f2bf(vv[j] - bf2f(h));
            }
            *(u16x8*)&sm.st.Ah[arow][akseg] = hi;
            *(u16x8*)&sm.st.Al[arow][akseg] = lo;
        }
        // ---- B: copy bf16 hi/lo tiles (96 rows x 32 k each) ----
        {
            const unsigned short* __restrict__ src = bhalf ? Bl : Bh;
            unsigned short (*dst)[PK] = bhalf ? sm.st.Bl : sm.st.Bh;
            #pragma unroll
            for (int c = 0; c < 3; c++) {
                const int row = c * 32 + brow;
                *(u16x8*)&dst[row][bkseg] =
                    *(const u16x8*)&src[(bn0 + row) * NF + k0 + bkseg];
            }
        }
        __syncthreads();

        #pragma unroll
        for (int im = 0; im < 2; im++) {
            const bf16x8 a_h = *(const bf16x8*)&sm.st.Ah[wm * 32 + im * 16 + l15][quad * 8];
            const bf16x8 a_l = *(const bf16x8*)&sm.st.Al[wm * 32 + im * 16 + l15][quad * 8];
            #pragma unroll
            for (int in = 0; in < 3; in++) {
                const bf16x8 b_h = *(const bf16x8*)&sm.st.Bh[wn * 48 + in * 16 + l15][quad * 8];
                const bf16x8 b_l = *(const bf16x8*)&sm.st.Bl[wn * 48 + in * 16 + l15][quad * 8];
                acc[im][in] = __builtin_amdgcn_mfma_f32_16x16x32_bf16(a_h, b_h, acc[im][in], 0, 0, 0);
                acc[im][in] = __builtin_amdgcn_mfma_f32_16x16x32_bf16(a_h, b_l, acc[im][in], 0, 0, 0);
                acc[im][in] = __builtin_amdgcn_mfma_f32_16x16x32_bf16(a_l, b_h, acc[im][in], 0, 0, 0);
            }
        }
        __syncthreads();
    }

    // ---- epilogue: fv -> LDS (C/D map: row=quad*4+r, col=l15) ----
    #pragma unroll
    for (int im = 0; im < 2; im++)
        #pragma unroll
        for (int in = 0; in < 3; in++)
            #pragma unroll
            for (int r = 0; r < 4; r++) {
                const int m = wm * 32 + im * 16 + quad * 4 + r;
                const int n = wn * 48 + in * 16 + l15;
                sm.ep.fv[m][n] = acc[im][in][r];
            }
    {
        const int tr  = tid >> 4;
        const int seg = (tid & 15) * 4;
        *(f32x4*)&sm.ep.resp[tr][seg] = *(const f32x4*)&resp_g[(t0 + tr) * NLEAF + seg];
    }
    if (tid < 16 * ND)       sm.ep.th[tid]      = thr[t0 * ND + tid];
    else if (tid < 32 * ND)  sm.ep.sc[tid - 96] = __expf(-ltemp[t0 * ND + tid - 96]);
    __syncthreads();

    // ---- tree evaluation: lane -> (m-row, tree); 16 consecutive trees per
    //      16 lanes => coalesced 64B output segments ----
    const int t16 = tid & 15;
    const int mr  = tid >> 4;     // 0..15
    #pragma unroll
    for (int i = 0; i < 4; i++) {
        const int m = mr + 16 * i;

        float sp[ND], sn[ND];
        #pragma unroll
        for (int d = 0; d < ND; d++) {
            const float f  = sm.ep.fv[m][t16 * ND + d];
            const float tl = (f - sm.ep.th[t16 * ND + d]) * sm.ep.sc[t16 * ND + d];
            const float h  = 0.5f * tl;
            sp[d] = fminf(fmaxf(0.5f + h, 0.0f), 1.0f);  // bit==0 factor
            sn[d] = fminf(fmaxf(0.5f - h, 0.0f), 1.0f);  // bit==1 factor
        }

        // fold-down contraction: out = sum_c resp[c] * prod_d s_d(bit_d(c))
        float r[32];
        #pragma unroll
        for (int c = 0; c < 32; c++)
            r[c] = sp[5] * sm.ep.resp[t16][c] + sn[5] * sm.ep.resp[t16][c + 32];
        #pragma unroll
        for (int d = 4; d >= 0; d--) {
            const int half = 1 << d;
            #pragma unroll
            for (int c = 0; c < 32; c++)
                if (c < half) r[c] = sp[d] * r[c] + sn[d] * r[c + half];
        }

        out[(bm0 + m) * NT + t0 + t16] = r[0];
    }
}

// ---------------------------------------------------------------------------
extern "C" void kernel_launch(void* const* d_in, const int* in_sizes, int n_in,
                              void* d_out, int out_size, void* d_ws, size_t ws_size,
                              hipStream_t stream)
{
    const float* x    = (const float*)d_in[0];  // [2048, 256]
    const float* resp = (const float*)d_in[1];  // [256, 1, 64]
    const float* fsl  = (const float*)d_in[2];  // [256, 256*6]
    const float* thr  = (const float*)d_in[3];  // [256, 6]
    const float* lt   = (const float*)d_in[4];  // [256, 6]
    float* out = (float*)d_out;                 // [2048, 256]

    unsigned short* fs_hi = (unsigned short*)d_ws;          // [NCOL, NF]
    unsigned short* fs_lo = fs_hi + (size_t)NCOL * NF;

    sparsemax_michelot<<<NCOL / 4, 256, 0, stream>>>(fsl, fs_hi, fs_lo);

    dim3 g(NCOL / TN, NB / TM);   // (16, 32)
    gemm_tree_kernel<<<g, 256, 0, stream>>>(x, fs_hi, fs_lo, thr, lt, resp, out);
}

// Round 4
// 90.016 us; speedup vs baseline: 1.1639x; 1.1639x over previous
//
#include <hip/hip_runtime.h>
#include <math.h>

#define NF 256      // in_features
#define NT 256      // num_trees
#define ND 6        // depth
#define NB 2048     // batch
#define NCOL (NT * ND)   // 1536
#define NLEAF 64         // 2^depth

typedef __attribute__((ext_vector_type(8))) short bf16x8;         // MFMA A/B frag
typedef __attribute__((ext_vector_type(4))) float f32x4;          // MFMA C/D frag
typedef __attribute__((ext_vector_type(8))) unsigned short u16x8; // 16B chunk

__device__ inline unsigned short f2bf(float f) {   // round-to-nearest-even bf16
    unsigned u = __float_as_uint(f);
    u += 0x7fffu + ((u >> 16) & 1u);
    return (unsigned short)(u >> 16);
}
__device__ inline float bf2f(unsigned short h) {
    return __uint_as_float(((unsigned)h) << 16);
}

// ---------------------------------------------------------------------------
// Kernel 1: sparsemax per (tree,depth) column via Michelot fixed-point.
// One wave per column, 4 elements/lane, shuffle reductions only (no LDS).
// Output TRANSPOSED [col][feature] bf16 hi/lo.
// ---------------------------------------------------------------------------
__global__ __launch_bounds__(256) void sparsemax_michelot(
    const float* __restrict__ fsl,       // [NF, NCOL]
    unsigned short* __restrict__ fs_hi,  // [NCOL, NF]
    unsigned short* __restrict__ fs_lo)  // [NCOL, NF]
{
    const int lane = threadIdx.x & 63;
    const int col  = blockIdx.x * 4 + (threadIdx.x >> 6);

    float x[4];
    #pragma unroll
    for (int j = 0; j < 4; j++)
        x[j] = fsl[(lane + 64 * j) * NCOL + col];

    // max over 256
    float mx = fmaxf(fmaxf(x[0], x[1]), fmaxf(x[2], x[3]));
    #pragma unroll
    for (int off = 32; off > 0; off >>= 1)
        mx = fmaxf(mx, __shfl_xor(mx, off));
    #pragma unroll
    for (int j = 0; j < 4; j++) x[j] -= mx;

    // tau_0 = (sum - 1)/256
    float s = (x[0] + x[1]) + (x[2] + x[3]);
    #pragma unroll
    for (int off = 32; off > 0; off >>= 1)
        s += __shfl_xor(s, off);
    float tau = (s - 1.0f) / 256.0f;

    // Michelot: S <- {x > tau}; tau <- (sum_S - 1)/|S|; stop when |S| stable.
    int prev = 256;
    for (int it = 0; it < 64; it++) {
        float ss = 0.0f, cc = 0.0f;
        #pragma unroll
        for (int j = 0; j < 4; j++)
            if (x[j] > tau) { ss += x[j]; cc += 1.0f; }
        #pragma unroll
        for (int off = 32; off > 0; off >>= 1) {
            ss += __shfl_xor(ss, off);
            cc += __shfl_xor(cc, off);
        }
        const int c = (int)cc;
        if (c == prev) break;
        prev = c;
        tau = (ss - 1.0f) / cc;
    }

    #pragma unroll
    for (int j = 0; j < 4; j++) {
        const float v = fmaxf(x[j] - tau, 0.0f);
        const unsigned short h = f2bf(v);
        fs_hi[col * NF + lane + 64 * j] = h;
        fs_lo[col * NF + lane + 64 * j] = f2bf(v - bf2f(h));
    }
}

// ---------------------------------------------------------------------------
// Kernel 2: fused split-bf16 MFMA GEMM + tree evaluation.
// Tile 64(M) x 96(N): 96 cols = 16 complete trees -> tree eval in epilogue,
// fv never hits global memory. A staged from fp32 x with in-register split.
// ---------------------------------------------------------------------------
#define TM 64
#define TN 96
#define TK 32
#define PK (TK + 8)   // padded LDS pitch (u16) to break bank conflicts

union SMem {
    struct {
        unsigned short Ah[TM][PK], Al[TM][PK];
        unsigned short Bh[TN][PK], Bl[TN][PK];
    } st;                                   // 25.0 KB (K-loop)
    struct {
        float fv[TM][TN + 1];               // 64 x 97
        float resp[16][NLEAF];              // 4 KB
    } ep;                                   // 28.25 KB (epilogue)
};

__global__ __launch_bounds__(256) void gemm_tree_kernel(
    const float* __restrict__ x,             // [NB, NF] fp32
    const unsigned short* __restrict__ Bh,   // fs hi [NCOL, NF]
    const unsigned short* __restrict__ Bl,   // fs lo [NCOL, NF]
    const float* __restrict__ thr,           // [NT, ND]
    const float* __restrict__ ltemp,         // [NT, ND]
    const float* __restrict__ resp_g,        // [NT, 1, NLEAF]
    float* __restrict__ out)                 // [NB, NT]
{
    __shared__ SMem sm;

    const int tid  = threadIdx.x;
    const int lane = tid & 63;
    const int w    = tid >> 6;
    const int wm   = w & 1;          // wave M pos (0..1) -> 32 rows
    const int wn   = w >> 1;         // wave N pos (0..1) -> 48 cols
    const int bm0  = blockIdx.y * TM;
    const int bn0  = blockIdx.x * TN;
    const int t0   = blockIdx.x * 16;    // first tree of this block

    const int l15  = lane & 15;
    const int quad = lane >> 4;

    // A staging coords: thread -> (row 0..63, kseg 0/8/16/24)
    const int arow  = tid >> 2;
    const int akseg = (tid & 3) * 8;
    // B staging coords: 128 threads hi, 128 threads lo; 32 rows x 32 k per pass
    const int bhalf = tid >> 7;
    const int brow  = (tid & 127) >> 2;
    const int bkseg = (tid & 3) * 8;

    f32x4 acc[2][3] = {};

    for (int k0 = 0; k0 < NF; k0 += TK) {
        // ---- A: load fp32, split to bf16 hi/lo in-register ----
        {
            const float4 v0 = *(const float4*)&x[(bm0 + arow) * NF + k0 + akseg];
            const float4 v1 = *(const float4*)&x[(bm0 + arow) * NF + k0 + akseg + 4];
            const float vv[8] = {v0.x, v0.y, v0.z, v0.w, v1.x, v1.y, v1.z, v1.w};
            u16x8 hi, lo;
            #pragma unroll
            for (int j = 0; j < 8; j++) {
                const unsigned short h = f2bf(vv[j]);
                hi[j] = h;
                lo[j] = f2bf(vv[j] - bf2f(h));
            }
            *(u16x8*)&sm.st.Ah[arow][akseg] = hi;
            *(u16x8*)&sm.st.Al[arow][akseg] = lo;
        }
        // ---- B: copy bf16 hi/lo tiles (96 rows x 32 k each) ----
        {
            const unsigned short* __restrict__ src = bhalf ? Bl : Bh;
            unsigned short (*dst)[PK] = bhalf ? sm.st.Bl : sm.st.Bh;
            #pragma unroll
            for (int c = 0; c < 3; c++) {
                const int row = c * 32 + brow;
                *(u16x8*)&dst[row][bkseg] =
                    *(const u16x8*)&src[(bn0 + row) * NF + k0 + bkseg];
            }
        }
        __syncthreads();

        #pragma unroll
        for (int im = 0; im < 2; im++) {
            const bf16x8 a_h = *(const bf16x8*)&sm.st.Ah[wm * 32 + im * 16 + l15][quad * 8];
            const bf16x8 a_l = *(const bf16x8*)&sm.st.Al[wm * 32 + im * 16 + l15][quad * 8];
            #pragma unroll
            for (int in = 0; in < 3; in++) {
                const bf16x8 b_h = *(const bf16x8*)&sm.st.Bh[wn * 48 + in * 16 + l15][quad * 8];
                const bf16x8 b_l = *(const bf16x8*)&sm.st.Bl[wn * 48 + in * 16 + l15][quad * 8];
                acc[im][in] = __builtin_amdgcn_mfma_f32_16x16x32_bf16(a_h, b_h, acc[im][in], 0, 0, 0);
                acc[im][in] = __builtin_amdgcn_mfma_f32_16x16x32_bf16(a_h, b_l, acc[im][in], 0, 0, 0);
                acc[im][in] = __builtin_amdgcn_mfma_f32_16x16x32_bf16(a_l, b_h, acc[im][in], 0, 0, 0);
            }
        }
        __syncthreads();
    }

    // ---- epilogue: fv -> LDS (C/D map: row=quad*4+r, col=l15), stage resp ----
    #pragma unroll
    for (int im = 0; im < 2; im++)
        #pragma unroll
        for (int in = 0; in < 3; in++)
            #pragma unroll
            for (int r = 0; r < 4; r++) {
                const int m = wm * 32 + im * 16 + quad * 4 + r;
                const int n = wn * 48 + in * 16 + l15;
                sm.ep.fv[m][n] = acc[im][in][r];
            }
    {
        const int tr  = tid >> 4;
        const int seg = (tid & 15) * 4;
        *(float4*)&sm.ep.resp[tr][seg] = *(const float4*)&resp_g[(t0 + tr) * NLEAF + seg];
    }
    __syncthreads();

    // ---- tree evaluation: 64 rows x 16 trees = 1024 items, 4 per thread ----
    #pragma unroll
    for (int i = 0; i < 4; i++) {
        const int item = tid + 256 * i;
        const int m    = item & 63;
        const int t16  = item >> 6;
        const int t    = t0 + t16;

        float sp[ND], sn[ND];
        #pragma unroll
        for (int d = 0; d < ND; d++) {
            const float f  = sm.ep.fv[m][t16 * ND + d];
            const float tl = (f - thr[t * ND + d]) * __expf(-ltemp[t * ND + d]);
            const float h  = 0.5f * tl;
            sp[d] = fminf(fmaxf(0.5f + h, 0.0f), 1.0f);  // bit==0 factor
            sn[d] = fminf(fmaxf(0.5f - h, 0.0f), 1.0f);  // bit==1 factor
        }

        float wleaf[NLEAF];
        wleaf[0] = 1.0f;
        #pragma unroll
        for (int d = 0; d < ND; d++) {
            const int half = 1 << d;
            #pragma unroll
            for (int c = 0; c < NLEAF / 2; c++) {
                if (c < half) {
                    const float base = wleaf[c];
                    wleaf[c + half] = base * sn[d];
                    wleaf[c]        = base * sp[d];
                }
            }
        }

        float a = 0.0f;
        #pragma unroll
        for (int c = 0; c < NLEAF; c++)
            a = fmaf(wleaf[c], sm.ep.resp[t16][c], a);

        out[(bm0 + m) * NT + t] = a;
    }
}

// ---------------------------------------------------------------------------
extern "C" void kernel_launch(void* const* d_in, const int* in_sizes, int n_in,
                              void* d_out, int out_size, void* d_ws, size_t ws_size,
                              hipStream_t stream)
{
    const float* x    = (const float*)d_in[0];  // [2048, 256]
    const float* resp = (const float*)d_in[1];  // [256, 1, 64]
    const float* fsl  = (const float*)d_in[2];  // [256, 256*6]
    const float* thr  = (const float*)d_in[3];  // [256, 6]
    const float* lt   = (const float*)d_in[4];  // [256, 6]
    float* out = (float*)d_out;                 // [2048, 256]

    unsigned short* fs_hi = (unsigned short*)d_ws;          // [NCOL, NF]
    unsigned short* fs_lo = fs_hi + (size_t)NCOL * NF;

    sparsemax_michelot<<<NCOL / 4, 256, 0, stream>>>(fsl, fs_hi, fs_lo);

    dim3 g(NCOL / TN, NB / TM);   // (16, 32)
    gemm_tree_kernel<<<g, 256, 0, stream>>>(x, fs_hi, fs_lo, thr, lt, resp, out);
}